// Round 2
// baseline (673.660 us; speedup 1.0000x reference)
//
#include <hip/hip_runtime.h>
#include <hip/hip_bf16.h>

typedef float f32x4 __attribute__((ext_vector_type(4)));

#define NTOT   65536
#define DDIM   256
#define KCODES 1024
#define BRR    128   // rows per block
#define BCC    128   // codes per k-tile
#define BDD    32    // d per LDS tile
#define ZST    132   // 128 + 4 pad; 132*4B = 16B-aligned rows, bank shift of 4/row

// ---------------- kernel 1: wsq[k] = ||w_k||^2 ----------------
__global__ __launch_bounds__(256) void wsq_kernel(const float* __restrict__ w,
                                                  float* __restrict__ wsq) {
  int k = blockIdx.x * 256 + threadIdx.x;
  if (k >= KCODES) return;
  const f32x4* wr = (const f32x4*)(w + (size_t)k * DDIM);
  float s = 0.f;
#pragma unroll 8
  for (int j = 0; j < DDIM / 4; ++j) {
    f32x4 v = wr[j];
    s += v[0] * v[0] + v[1] * v[1] + v[2] * v[2] + v[3] * v[3];
  }
  wsq[k] = s;
}

// ---------------- kernel 2: fused distance + argmin + gather + loss ----------------
__global__ __launch_bounds__(256, 4) void vq_main(
    const float* __restrict__ z, const float* __restrict__ w,
    const float* __restrict__ wsq, float* __restrict__ loss_accum,
    float* __restrict__ out) {
  __shared__ float zs[BDD * ZST];   // z tile, transposed [dd][row]
  __shared__ float wls[BDD * ZST];  // w tile, transposed [dd][code]
  __shared__ int   sidx[BRR];
  __shared__ float wsum[4];

  const int tid = threadIdx.x;
  const int tc = tid & 15, tr = tid >> 4;
  const int tr4 = tr * 4, tc4 = tc * 4;
  const int br = blockIdx.x * BRR;

  float minv[8];
  int   mini[8];
#pragma unroll
  for (int i = 0; i < 8; ++i) { minv[i] = 3.4e38f; mini[i] = 0; }

  for (int kt = 0; kt < KCODES / BCC; ++kt) {
    const int kb = kt * BCC;
    float acc[8][8];
#pragma unroll
    for (int i = 0; i < 8; ++i)
#pragma unroll
      for (int j = 0; j < 8; ++j) acc[i][j] = 0.f;

    for (int dt = 0; dt < DDIM / BDD; ++dt) {
      const int d0 = dt * BDD;
      __syncthreads();  // protect previous tile's readers
      // stage z-tile [128 rows][32 d] and w-tile [128 codes][32 d], transposed
#pragma unroll
      for (int it = 0; it < 4; ++it) {
        int f = tid + 256 * it;
        int row = f >> 3;
        int c4 = (f & 7) * 4;
        f32x4 zv = *(const f32x4*)&z[(size_t)(br + row) * DDIM + d0 + c4];
        f32x4 wv = *(const f32x4*)&w[(size_t)(kb + row) * DDIM + d0 + c4];
#pragma unroll
        for (int j = 0; j < 4; ++j) {
          zs[(c4 + j) * ZST + row]  = zv[j];
          wls[(c4 + j) * ZST + row] = wv[j];
        }
      }
      __syncthreads();
#pragma unroll 4
      for (int dd = 0; dd < BDD; ++dd) {
        f32x4 za = *(const f32x4*)&zs[dd * ZST + tr4];
        f32x4 zb = *(const f32x4*)&zs[dd * ZST + 64 + tr4];
        f32x4 wa = *(const f32x4*)&wls[dd * ZST + tc4];
        f32x4 wb = *(const f32x4*)&wls[dd * ZST + 64 + tc4];
#pragma unroll
        for (int i = 0; i < 4; ++i)
#pragma unroll
          for (int j = 0; j < 4; ++j) {
            acc[i][j]         = fmaf(za[i], wa[j], acc[i][j]);
            acc[i][j + 4]     = fmaf(za[i], wb[j], acc[i][j + 4]);
            acc[i + 4][j]     = fmaf(zb[i], wa[j], acc[i + 4][j]);
            acc[i + 4][j + 4] = fmaf(zb[i], wb[j], acc[i + 4][j + 4]);
          }
      }
    }
    // epilogue: score = wsq - 2*dot, running argmin (codes ascending -> first-tie wins)
#pragma unroll
    for (int j8 = 0; j8 < 8; ++j8) {
      int cl = (j8 < 4) ? (tc4 + j8) : (64 + tc4 + j8 - 4);
      int cg = kb + cl;
      float q = wsq[cg];
#pragma unroll
      for (int i8 = 0; i8 < 8; ++i8) {
        float score = fmaf(-2.f, acc[i8][j8], q);
        if (score < minv[i8]) { minv[i8] = score; mini[i8] = cg; }
      }
    }
  }

  // ---- cross-thread argmin reduce (16 tc candidates per row) ----
  __syncthreads();
  float* redv = zs;         // reuse LDS
  int*   redi = (int*)wls;  // reuse LDS
#pragma unroll
  for (int i8 = 0; i8 < 8; ++i8) {
    int rl = (i8 < 4) ? (tr4 + i8) : (64 + tr4 + i8 - 4);
    redv[rl * 16 + tc] = minv[i8];
    redi[rl * 16 + tc] = mini[i8];
  }
  __syncthreads();
  if (tid < BRR) {
    float bv = redv[tid * 16];
    int   bi = redi[tid * 16];
    for (int t = 1; t < 16; ++t) {
      float v = redv[tid * 16 + t];
      int  ii = redi[tid * 16 + t];
      if (v < bv || (v == bv && ii < bi)) { bv = v; bi = ii; }
    }
    sidx[tid] = bi;
    // indices region: fp32 elements [1 + NTOT*DDIM, 1 + NTOT*DDIM + NTOT)
    out[(size_t)1 + (size_t)NTOT * DDIM + br + tid] = (float)bi;
  }
  __syncthreads();

  // ---- gather z_q, write fp32 z_q_st = z + (z_q - z), accumulate commitment loss ----
  float lsum = 0.f;
  for (int r = 0; r < BRR; ++r) {
    int idx = sidx[r];
    float qv = w[(size_t)idx * DDIM + tid];
    float zv = z[(size_t)(br + r) * DDIM + tid];
    float df = qv - zv;                 // stop_grad(z_q - z), fp32 rounding like ref
    out[1 + (size_t)(br + r) * DDIM + tid] = zv + df;  // straight-through estimate
    lsum = fmaf(df, df, lsum);
  }
#pragma unroll
  for (int off = 32; off > 0; off >>= 1) lsum += __shfl_down(lsum, off, 64);
  if ((tid & 63) == 0) wsum[tid >> 6] = lsum;
  __syncthreads();
  if (tid == 0) atomicAdd(loss_accum, wsum[0] + wsum[1] + wsum[2] + wsum[3]);
}

// ---------------- kernel 3: finalize loss ----------------
__global__ void vq_finalize(const float* __restrict__ loss_accum,
                            float* __restrict__ out) {
  out[0] = 0.25f * loss_accum[0] * (1.0f / 16777216.0f);
}

extern "C" void kernel_launch(void* const* d_in, const int* in_sizes, int n_in,
                              void* d_out, int out_size, void* d_ws, size_t ws_size,
                              hipStream_t stream) {
  const float* z = (const float*)d_in[0];
  const float* w = (const float*)d_in[1];
  float* out = (float*)d_out;
  float* wsf = (float*)d_ws;

  hipMemsetAsync(d_ws, 0, 4, stream);  // zero the loss accumulator (ws[0])
  wsq_kernel<<<dim3(KCODES / 256), dim3(256), 0, stream>>>(w, wsf + 16);
  vq_main<<<dim3(NTOT / BRR), dim3(256), 0, stream>>>(z, w, wsf + 16, wsf, out);
  vq_finalize<<<dim3(1), dim3(1), 0, stream>>>(wsf, out);
}